// Round 11
// baseline (2576.304 us; speedup 1.0000x reference)
//
#include <hip/hip_runtime.h>

// CharLSTM forward: B=16, T=256, H=1024, V=32000
//   P0 prep: fuse/transpose weights to bf16, embed gather, init ctl
//   fused kernel (256 blocks x 512 thr, 1 block/CU via 132KB LDS):
//     blocks 0-31 (workers): persistent recurrence; per-wave flag polling
//       (no reader barrier); line-layout H exchange via MALL (r10-proven);
//       gated on Gx row counters; worker wave 0 publishes PROG.
//     blocks 32-255 (consumers): phase 1 = produce 1024 Gx tiles (ticket
//       queue, t-ascending, agent stores, GXR row counters); phase 2 = Ys
//       strips, strip-outer/mt-inner (WqT staged ONCE per strip).

typedef __bf16 bf16_t;
typedef bf16_t bf16x8 __attribute__((ext_vector_type(8)));
typedef bf16_t bf16x4 __attribute__((ext_vector_type(4)));
typedef float f32x4 __attribute__((ext_vector_type(4)));
typedef unsigned short u16;
typedef unsigned int u32;
typedef unsigned long long u64;

#define B_ 16
#define T_ 256
#define H_ 1024
#define V_ 32000
#define NWORK 32
#define NCONS 224
#define NSTRIP 500
#define FLAG_STRIDE 16
// ctl u32 offsets
#define FL    0                   // + wid*16 : 32 block step flags
#define GXR   512                 // + mt*16  : 32 Gx row-block counters
#define WQ    1024                // ticket
#define PROG  1040                // recurrence progress (steps complete)
#define CTL_WORDS 1056
#define BSROW 1032                // padded LDS row (u16) = 2064 B

__device__ __forceinline__ u16 f2bf(float x) {
  union { float f; u32 u; } v; v.f = x;
  u32 r = v.u + 0x7FFFu + ((v.u >> 16) & 1u);
  return (u16)(r >> 16);
}
__device__ __forceinline__ bf16x8 ldb8(const u16* p) {
  return *reinterpret_cast<const bf16x8*>(p);
}
__device__ __forceinline__ bf16x8 mk2(const u16* p) {
  bf16x4 lo = *reinterpret_cast<const bf16x4*>(p);
  bf16x4 hi = *reinterpret_cast<const bf16x4*>(p + 64);
  return __builtin_shufflevector(lo, hi, 0, 1, 2, 3, 4, 5, 6, 7);
}
__device__ __forceinline__ float fsig(float x) {
  return __builtin_amdgcn_rcpf(1.0f + __expf(-x));
}
__device__ __forceinline__ float ftanh(float x) {
  float x2 = fminf(fmaxf(2.0f * x, -80.0f), 80.0f);
  float e = __expf(x2);
  return (e - 1.0f) * __builtin_amdgcn_rcpf(e + 1.0f);
}
__device__ __forceinline__ void gll16(const void* g, void* l) {
  __builtin_amdgcn_global_load_lds(
      (const __attribute__((address_space(1))) void*)g,
      (__attribute__((address_space(3))) void*)l, 16, 0, 0);
}
__device__ __forceinline__ u32 ld_agent(const u32* p) {
  return __hip_atomic_load(p, __ATOMIC_RELAXED, __HIP_MEMORY_SCOPE_AGENT);
}
__device__ __forceinline__ void st_agent(u32* p, u32 v) {
  __hip_atomic_store(p, v, __ATOMIC_RELAXED, __HIP_MEMORY_SCOPE_AGENT);
}
__device__ __forceinline__ void st_agent64(u64* p, u64 v) {
  __hip_atomic_store(p, v, __ATOMIC_RELAXED, __HIP_MEMORY_SCOPE_AGENT);
}

// ---------------- prep kernels ----------------

__global__ void k_init(u32* Hs0u32, u32* ctl, float* bfu,
                       const float* b0, const float* b1, const float* b2, const float* b3) {
  int i = blockIdx.x * 256 + threadIdx.x;   // 16384
  if (i < 8192)
    __hip_atomic_store(&Hs0u32[i], 0u, __ATOMIC_RELAXED, __HIP_MEMORY_SCOPE_AGENT);
  if (i < CTL_WORDS)
    st_agent(&ctl[i], 0u);
  if (i < 4096) {
    int g = i >> 10, u = i & 1023;
    const float* bb = (g == 0) ? b0 : (g == 1) ? b1 : (g == 2) ? b2 : b3;
    bfu[i] = bb[u];
  }
}

__global__ void k_embed(const int* __restrict__ ids, const float* __restrict__ emb,
                        u16* __restrict__ out) {
  int r = blockIdx.x;               // r = t*16 + b
  int t = r >> 4, b = r & 15;
  int row = ids[b * T_ + t];
  const f32x4 v = *(const f32x4*)&emb[(size_t)row * H_ + threadIdx.x * 4];
  ushort4 o;
  o.x = f2bf(v[0]); o.y = f2bf(v[1]); o.z = f2bf(v[2]); o.w = f2bf(v[3]);
  *(ushort4*)&out[(size_t)r * H_ + threadIdx.x * 4] = o;
}

__global__ void k_fuse8(const float* __restrict__ Wxi, const float* __restrict__ Wxf,
                        const float* __restrict__ Wxo, const float* __restrict__ Wxc,
                        const float* __restrict__ Whi, const float* __restrict__ Whf,
                        const float* __restrict__ Who, const float* __restrict__ Whc,
                        u16* __restrict__ WxT, u16* __restrict__ WhT) {
  __shared__ float ti[64][65];
  int z = blockIdx.z, g = z & 3;
  const float* W;
  if (z < 4) W = (g == 0) ? Wxi : (g == 1) ? Wxf : (g == 2) ? Wxo : Wxc;
  else       W = (g == 0) ? Whi : (g == 1) ? Whf : (g == 2) ? Who : Whc;
  u16* WT = (z < 4) ? WxT : WhT;
  int u0 = blockIdx.x * 64, k0 = blockIdx.y * 64;
  int c = threadIdx.x & 63, rq = threadIdx.x >> 6;
#pragma unroll
  for (int p = 0; p < 16; ++p) {
    int rr = p * 4 + rq;
    ti[rr][c] = W[(size_t)(k0 + rr) * H_ + u0 + c];
  }
  __syncthreads();
#pragma unroll
  for (int p = 0; p < 16; ++p) {
    int uu = p * 4 + rq;
    WT[(size_t)(g * H_ + u0 + uu) * H_ + k0 + c] = f2bf(ti[c][uu]);
  }
}

__global__ void k_transq(const float* __restrict__ Whq, u16* __restrict__ WqT) {
  __shared__ float ti[64][65];
  int n0 = blockIdx.x * 64, k0 = blockIdx.y * 64;
  int c = threadIdx.x & 63, rq = threadIdx.x >> 6;
#pragma unroll
  for (int p = 0; p < 16; ++p) {
    int rr = p * 4 + rq;
    ti[rr][c] = Whq[(size_t)(k0 + rr) * V_ + n0 + c];
  }
  __syncthreads();
#pragma unroll
  for (int p = 0; p < 16; ++p) {
    int nn = p * 4 + rq;
    WqT[(size_t)(n0 + nn) * H_ + k0 + c] = f2bf(ti[c][nn]);
  }
}

// ---------------- fused kernel ----------------
__global__ __launch_bounds__(512)
void fused(const u16* __restrict__ WhT, const u16* __restrict__ WxT,
           const u16* __restrict__ WqT, const u16* __restrict__ Emb,
           float* __restrict__ Gx, u16* __restrict__ Hs,
           u32* __restrict__ ctl, const float* __restrict__ bfu,
           const float* __restrict__ bqv, float* __restrict__ out,
           float* __restrict__ outH, float* __restrict__ outC) {
  __shared__ __align__(16) char ldsbuf[132096];
  __shared__ u32 s_tk;
  const int bid = blockIdx.x;
  const int tid = threadIdx.x, l = tid & 63, w = tid >> 6;

  if (bid < NWORK) {
    // =============== WORKER: persistent recurrence ===============
    float (*gx)[16][16] = (float (*)[16][16])ldsbuf;
    const int wid = bid;
    const int gw = wid * 8 + w;                   // 0..255
    const int hu0 = gw * 4;
    const int c = l & 15;
    const int n = (c >> 2) * H_ + hu0 + (c & 3);
    const int koff = (l >> 4) * 8;
    const int kgrp = (l >> 4) * 2;
    const int m = l & 15, u = l >> 4;
    const int hu = hu0 + u;
    const int m4 = m * 4;

    bf16x8 wf[32];
    {
      const u16* bp = WhT + (size_t)n * H_ + koff;
#pragma unroll
      for (int kk = 0; kk < 32; ++kk) wf[kk] = ldb8(bp + kk * 32);
    }

    float Cs = 0.0f;
    u64* HsU64 = (u64*)Hs;
    const u32* myflag = &ctl[FL + (l & 31) * FLAG_STRIDE];

    for (int t = 0; t < T_; ++t) {
      // gate on Gx row-block availability (consumers produce t-ascending)
      if ((t & 7) == 0) {
        while (ld_agent(&ctl[GXR + (t >> 3) * FLAG_STRIDE]) < 32u)
          __builtin_amdgcn_s_sleep(2);
      }
      const f32x4 g4 = *(const f32x4*)&Gx[((size_t)t * 4096 + n) * 16 + (size_t)(l >> 4) * 4];

      if (t > 0) {
        // per-wave independent poll of the 32 block flags (no reader barrier)
        while (true) {
          u32 v = ld_agent(myflag);
          if (__all((int)(v >= (u32)t))) break;
          __builtin_amdgcn_s_sleep(2);
        }
        if (gw == 0 && l == 0) st_agent(&ctl[PROG], (u32)t);
      }

      const u16* hrow = Hs + (size_t)t * 16384 + m4;
      f32x4 a0 = {}, a1 = {}, a2 = {}, a3 = {};
#pragma unroll
      for (int kk = 0; kk < 32; kk += 4) {
        a0 = __builtin_amdgcn_mfma_f32_16x16x32_bf16(mk2(hrow + (kgrp + (kk + 0) * 8) * 64), wf[kk + 0], a0, 0, 0, 0);
        a1 = __builtin_amdgcn_mfma_f32_16x16x32_bf16(mk2(hrow + (kgrp + (kk + 1) * 8) * 64), wf[kk + 1], a1, 0, 0, 0);
        a2 = __builtin_amdgcn_mfma_f32_16x16x32_bf16(mk2(hrow + (kgrp + (kk + 2) * 8) * 64), wf[kk + 2], a2, 0, 0, 0);
        a3 = __builtin_amdgcn_mfma_f32_16x16x32_bf16(mk2(hrow + (kgrp + (kk + 3) * 8) * 64), wf[kk + 3], a3, 0, 0, 0);
      }
      f32x4 acc = (a0 + a1) + (a2 + a3);

#pragma unroll
      for (int j = 0; j < 4; ++j)
        gx[w][(l >> 4) * 4 + j][c] = acc[j] + g4[j];

      float gi = gx[w][m][0 + u];
      float gf = gx[w][m][4 + u];
      float go = gx[w][m][8 + u];
      float gc = gx[w][m][12 + u];
      float I = fsig(gi);
      float F = fsig(gf);
      float O = fsig(go);
      float Ct = ftanh(gc);
      Cs = F * Cs + I * Ct;
      float Hn = O * ftanh(Cs);

      u32 hb = (u32)f2bf(Hn);
      u32 h1 = __shfl_down(hb, 16);
      u32 h2 = __shfl_down(hb, 32);
      u32 h3 = __shfl_down(hb, 48);
      if (l < 16) {
        u64 pk = (u64)hb | ((u64)h1 << 16) | ((u64)h2 << 32) | ((u64)h3 << 48);
        st_agent64(&HsU64[(size_t)(t + 1) * 4096 + (size_t)gw * 16 + l], pk);
      }
      if (t == T_ - 1) {
        outH[(size_t)m * H_ + hu] = Hn;
        outC[(size_t)m * H_ + hu] = Cs;
      }

      // producer side: own stores acked, block-wide, then one flag store
      asm volatile("s_waitcnt vmcnt(0)" ::: "memory");
      __syncthreads();
      if (tid == 0) st_agent(&ctl[FL + wid * FLAG_STRIDE], (u32)(t + 1));
    }

    // publish final progress (Hs[256] visible)
    if (gw == 0) {
      while (true) {
        u32 v = ld_agent(myflag);
        if (__all((int)(v >= (u32)T_))) break;
        __builtin_amdgcn_s_sleep(2);
      }
      if (l == 0) st_agent(&ctl[PROG], (u32)T_);
    }
    return;
  }

  // =============== CONSUMER ===============
  const int cid = bid - NWORK;

  // ---- Phase 1: Gx tiles (ticket queue, t-ascending) ----
  {
    u16* As = (u16*)ldsbuf;          // [128][32] 8KB
    u16* Bs = As + 4096;             // [128][32] 8KB
    const int wm = (w & 1) * 64, wn = (w >> 1) * 32;
    const int koff = (l >> 4) * 8;
    const int srow = tid >> 2;                 // 0..127
    const int scol = (tid & 3) * 8;
    u16* dstA = As + (size_t)w * 512;          // wave-uniform; lane offset auto
    u16* dstB = Bs + (size_t)w * 512;

    for (;;) {
      __syncthreads();
      if (tid == 0)
        s_tk = __hip_atomic_fetch_add(&ctl[WQ], 1u, __ATOMIC_RELAXED, __HIP_MEMORY_SCOPE_AGENT);
      __syncthreads();
      u32 tk = s_tk;
      if (tk >= 1024u) break;
      const int mt = (int)(tk >> 5), nt = (int)(tk & 31);
      const int m0 = mt * 128, n0 = nt * 128;
      const u16* srcA = Emb + (size_t)(m0 + srow) * H_ + scol;
      const u16* srcB = WxT + (size_t)(n0 + srow) * H_ + scol;

      f32x4 acc[4][2] = {};
      for (int k0 = 0; k0 < H_; k0 += 32) {
        gll16(srcA + k0, dstA);
        gll16(srcB + k0, dstB);
        asm volatile("s_waitcnt vmcnt(0)" ::: "memory");
        __syncthreads();
        bf16x8 af[4], bfr[2];
#pragma unroll
        for (int tm = 0; tm < 4; ++tm)
          af[tm] = ldb8(&As[(wm + tm * 16 + (l & 15)) * 32 + koff]);
#pragma unroll
        for (int tn = 0; tn < 2; ++tn)
          bfr[tn] = ldb8(&Bs[(wn + tn * 16 + (l & 15)) * 32 + koff]);
#pragma unroll
        for (int tm = 0; tm < 4; ++tm)
#pragma unroll
          for (int tn = 0; tn < 2; ++tn)
            acc[tm][tn] = __builtin_amdgcn_mfma_f32_16x16x32_bf16(af[tm], bfr[tn], acc[tm][tn], 0, 0, 0);
        __syncthreads();
      }

#pragma unroll
      for (int tm = 0; tm < 4; ++tm) {
        int rbase = m0 + wm + tm * 16 + (l >> 4) * 4;
        int t = rbase >> 4;
        int bb = rbase & 15;
#pragma unroll
        for (int tn = 0; tn < 2; ++tn) {
          int nn = n0 + wn + tn * 16 + (l & 15);
          float bv = bfu[nn];
          union { float f[2]; u64 u; } p0, p1;
          p0.f[0] = acc[tm][tn][0] + bv; p0.f[1] = acc[tm][tn][1] + bv;
          p1.f[0] = acc[tm][tn][2] + bv; p1.f[1] = acc[tm][tn][3] + bv;
          u64* o = (u64*)&Gx[((size_t)t * 4096 + nn) * 16 + bb];
          st_agent64(&o[0], p0.u);
          st_agent64(&o[1], p1.u);
        }
      }
      asm volatile("s_waitcnt vmcnt(0)" ::: "memory");
      __syncthreads();
      if (tid == 0)
        __hip_atomic_fetch_add(&ctl[GXR + mt * FLAG_STRIDE], 1u, __ATOMIC_RELAXED, __HIP_MEMORY_SCOPE_AGENT);
    }
  }
  __syncthreads();

  // ---- Phase 2: Ys strips (strip-outer, mt-inner; WqT staged once) ----
  {
    u16* Bs = (u16*)ldsbuf;                     // [64][BSROW]
    const int nloc = (w & 3) * 16 + (l & 15);
    const int mhalf = w >> 2;
    const int koff = (l >> 4) * 8;
    const int kgrp = (l >> 4) * 2;
    const int m4 = (l & 15) * 4;
    const size_t tv = (size_t)T_ * V_;

    for (int s = cid; s < NSTRIP; s += NCONS) {
      const int n0 = s * 64;
#pragma unroll
      for (int r8 = 0; r8 < 8; ++r8) {
        int row = w * 8 + r8;
        const u16* src = WqT + (size_t)(n0 + row) * H_;
        u16* dst = Bs + row * BSROW;
        gll16(src + l * 8, dst);
        gll16(src + 512 + l * 8, dst + 512);
      }
      asm volatile("s_waitcnt vmcnt(0)" ::: "memory");
      __syncthreads();

      const u16* bsrow = Bs + nloc * BSROW + koff;
      const int nn = n0 + nloc;
      const float bv = bqv[nn];

      for (int mt = 0; mt < 32; ++mt) {
        if (tid == 0) {
          const u32 need = (u32)(mt * 8 + 8);
          while (ld_agent(&ctl[PROG]) < need)
            __builtin_amdgcn_s_sleep(16);
        }
        __syncthreads();

        f32x4 acc[4] = {};
        const u16* hbase = Hs + (size_t)(mt * 8 + mhalf * 4 + 1) * 16384 + m4;
#pragma unroll 4
        for (int kk = 0; kk < 32; ++kk) {
          bf16x8 bf = ldb8(bsrow + kk * 32);
          const int qo = (kgrp + kk * 8) * 64;
          acc[0] = __builtin_amdgcn_mfma_f32_16x16x32_bf16(mk2(hbase + 0 * 16384 + qo), bf, acc[0], 0, 0, 0);
          acc[1] = __builtin_amdgcn_mfma_f32_16x16x32_bf16(mk2(hbase + 1 * 16384 + qo), bf, acc[1], 0, 0, 0);
          acc[2] = __builtin_amdgcn_mfma_f32_16x16x32_bf16(mk2(hbase + 2 * 16384 + qo), bf, acc[2], 0, 0, 0);
          acc[3] = __builtin_amdgcn_mfma_f32_16x16x32_bf16(mk2(hbase + 3 * 16384 + qo), bf, acc[3], 0, 0, 0);
        }

#pragma unroll
        for (int tm = 0; tm < 4; ++tm) {
          const int t_glob = mt * 8 + mhalf * 4 + tm;
#pragma unroll
          for (int j = 0; j < 4; ++j) {
            out[(size_t)((l >> 4) * 4 + j) * tv + (size_t)t_glob * V_ + nn] = acc[tm][j] + bv;
          }
        }
      }
      __syncthreads();   // Bs reads done before next strip's staging
    }
  }
}

// ---------------- host launcher ----------------

extern "C" void kernel_launch(void* const* d_in, const int* in_sizes, int n_in,
                              void* d_out, int out_size, void* d_ws, size_t ws_size,
                              hipStream_t stream) {
  const int*   ids = (const int*)d_in[0];
  const float* emb = (const float*)d_in[1];
  const float* Wxi = (const float*)d_in[2];
  const float* Whi = (const float*)d_in[3];
  const float* bi  = (const float*)d_in[4];
  const float* Wxf = (const float*)d_in[5];
  const float* Whf = (const float*)d_in[6];
  const float* bfv = (const float*)d_in[7];
  const float* Wxo = (const float*)d_in[8];
  const float* Who = (const float*)d_in[9];
  const float* bo  = (const float*)d_in[10];
  const float* Wxc = (const float*)d_in[11];
  const float* Whc = (const float*)d_in[12];
  const float* bc  = (const float*)d_in[13];
  const float* Whq = (const float*)d_in[14];
  const float* bq  = (const float*)d_in[15];
  float* out = (float*)d_out;

  char* ws = (char*)d_ws;
  u16* WxT = (u16*)ws;      ws += (size_t)4096 * H_ * 2;
  u16* WhT = (u16*)ws;      ws += (size_t)4096 * H_ * 2;
  u16* WqT = (u16*)ws;      ws += (size_t)V_ * H_ * 2;
  u16* Emb = (u16*)ws;      ws += (size_t)T_ * B_ * H_ * 2;
  float* Gx = (float*)ws;   ws += (size_t)T_ * 4096 * B_ * 4;
  u16* Hs  = (u16*)ws;      ws += (size_t)(T_ + 1) * B_ * H_ * 2;
  float* bfu = (float*)ws;  ws += (size_t)4096 * 4;
  u32* ctl = (u32*)ws;      ws += (size_t)CTL_WORDS * 4;

  // prep
  k_init<<<64, 256, 0, stream>>>((u32*)Hs, ctl, bfu, bi, bfv, bo, bc);
  k_embed<<<4096, 256, 0, stream>>>(ids, emb, Emb);
  k_fuse8<<<dim3(16, 16, 8), 256, 0, stream>>>(Wxi, Wxf, Wxo, Wxc, Whi, Whf, Who, Whc, WxT, WhT);
  k_transq<<<dim3(500, 16), 256, 0, stream>>>(Whq, WqT);

  // fused: Gx producers + recurrence + Ys consumers
  float* outH = out + (size_t)B_ * T_ * V_;
  float* outC = outH + (size_t)B_ * H_;
  fused<<<NWORK + NCONS, 512, 0, stream>>>(WhT, WxT, WqT, Emb, Gx, Hs, ctl, bfu, bq,
                                           out, outH, outC);
}

// Round 13
// 1769.571 us; speedup vs baseline: 1.4559x; 1.4559x over previous
//
#include <hip/hip_runtime.h>

// CharLSTM forward: B=16, T=256, H=1024, V=32000
//   P0 prep: fuse/transpose weights to bf16, embed gather, init ctl
//   fused kernel (256 blocks x 512 thr, 1 block/CU via 132KB LDS):
//     blocks 0-31 (workers): persistent recurrence; r10 sync protocol
//       (wave0 flag poll + barrier; UNCONDITIONAL per-step flag store incl.
//       final step — r12's missing t=T-1 store caused the deadlock);
//       H[t] staged to LDS once per block per step (global_load_lds) ->
//       LDS-fed A-fragments; line-layout H stores via MALL; PROG published.
//     blocks 32-255 (consumers): phase 1 = produce 1024 Gx tiles (ticket
//       queue, t-ascending, agent stores, GXR row counters); phase 2 = Ys,
//       mt-outer/strip-inner (r10-proven pacing; WqT restaged per strip).

typedef __bf16 bf16_t;
typedef bf16_t bf16x8 __attribute__((ext_vector_type(8)));
typedef bf16_t bf16x4 __attribute__((ext_vector_type(4)));
typedef float f32x4 __attribute__((ext_vector_type(4)));
typedef unsigned short u16;
typedef unsigned int u32;
typedef unsigned long long u64;

#define B_ 16
#define T_ 256
#define H_ 1024
#define V_ 32000
#define NWORK 32
#define NCONS 224
#define NSTRIP 500
#define FLAG_STRIDE 16
// ctl u32 offsets
#define FL    0                   // + wid*16 : 32 block step flags
#define GXR   512                 // + mt*16  : 32 Gx row-block counters
#define WQ    1024                // ticket
#define PROG  1040                // recurrence progress (steps complete)
#define CTL_WORDS 1056
#define BSROW 1032                // padded LDS row (u16) = 2064 B

__device__ __forceinline__ u16 f2bf(float x) {
  union { float f; u32 u; } v; v.f = x;
  u32 r = v.u + 0x7FFFu + ((v.u >> 16) & 1u);
  return (u16)(r >> 16);
}
__device__ __forceinline__ bf16x8 ldb8(const u16* p) {
  return *reinterpret_cast<const bf16x8*>(p);
}
__device__ __forceinline__ bf16x8 mk2(const u16* p) {
  bf16x4 lo = *reinterpret_cast<const bf16x4*>(p);
  bf16x4 hi = *reinterpret_cast<const bf16x4*>(p + 64);
  return __builtin_shufflevector(lo, hi, 0, 1, 2, 3, 4, 5, 6, 7);
}
__device__ __forceinline__ float fsig(float x) {
  return __builtin_amdgcn_rcpf(1.0f + __expf(-x));
}
__device__ __forceinline__ float ftanh(float x) {
  float x2 = fminf(fmaxf(2.0f * x, -80.0f), 80.0f);
  float e = __expf(x2);
  return (e - 1.0f) * __builtin_amdgcn_rcpf(e + 1.0f);
}
__device__ __forceinline__ void gll16(const void* g, void* l) {
  __builtin_amdgcn_global_load_lds(
      (const __attribute__((address_space(1))) void*)g,
      (__attribute__((address_space(3))) void*)l, 16, 0, 0);
}
__device__ __forceinline__ u32 ld_agent(const u32* p) {
  return __hip_atomic_load(p, __ATOMIC_RELAXED, __HIP_MEMORY_SCOPE_AGENT);
}
__device__ __forceinline__ void st_agent(u32* p, u32 v) {
  __hip_atomic_store(p, v, __ATOMIC_RELAXED, __HIP_MEMORY_SCOPE_AGENT);
}
__device__ __forceinline__ void st_agent64(u64* p, u64 v) {
  __hip_atomic_store(p, v, __ATOMIC_RELAXED, __HIP_MEMORY_SCOPE_AGENT);
}

// ---------------- prep kernels ----------------

__global__ void k_init(u32* Hs0u32, u32* ctl, float* bfu,
                       const float* b0, const float* b1, const float* b2, const float* b3) {
  int i = blockIdx.x * 256 + threadIdx.x;   // 16384
  if (i < 8192)
    __hip_atomic_store(&Hs0u32[i], 0u, __ATOMIC_RELAXED, __HIP_MEMORY_SCOPE_AGENT);
  if (i < CTL_WORDS)
    st_agent(&ctl[i], 0u);
  if (i < 4096) {
    int g = i >> 10, u = i & 1023;
    const float* bb = (g == 0) ? b0 : (g == 1) ? b1 : (g == 2) ? b2 : b3;
    bfu[i] = bb[u];
  }
}

__global__ void k_embed(const int* __restrict__ ids, const float* __restrict__ emb,
                        u16* __restrict__ out) {
  int r = blockIdx.x;               // r = t*16 + b
  int t = r >> 4, b = r & 15;
  int row = ids[b * T_ + t];
  const f32x4 v = *(const f32x4*)&emb[(size_t)row * H_ + threadIdx.x * 4];
  ushort4 o;
  o.x = f2bf(v[0]); o.y = f2bf(v[1]); o.z = f2bf(v[2]); o.w = f2bf(v[3]);
  *(ushort4*)&out[(size_t)r * H_ + threadIdx.x * 4] = o;
}

__global__ void k_fuse8(const float* __restrict__ Wxi, const float* __restrict__ Wxf,
                        const float* __restrict__ Wxo, const float* __restrict__ Wxc,
                        const float* __restrict__ Whi, const float* __restrict__ Whf,
                        const float* __restrict__ Who, const float* __restrict__ Whc,
                        u16* __restrict__ WxT, u16* __restrict__ WhT) {
  __shared__ float ti[64][65];
  int z = blockIdx.z, g = z & 3;
  const float* W;
  if (z < 4) W = (g == 0) ? Wxi : (g == 1) ? Wxf : (g == 2) ? Wxo : Wxc;
  else       W = (g == 0) ? Whi : (g == 1) ? Whf : (g == 2) ? Who : Whc;
  u16* WT = (z < 4) ? WxT : WhT;
  int u0 = blockIdx.x * 64, k0 = blockIdx.y * 64;
  int c = threadIdx.x & 63, rq = threadIdx.x >> 6;
#pragma unroll
  for (int p = 0; p < 16; ++p) {
    int rr = p * 4 + rq;
    ti[rr][c] = W[(size_t)(k0 + rr) * H_ + u0 + c];
  }
  __syncthreads();
#pragma unroll
  for (int p = 0; p < 16; ++p) {
    int uu = p * 4 + rq;
    WT[(size_t)(g * H_ + u0 + uu) * H_ + k0 + c] = f2bf(ti[c][uu]);
  }
}

__global__ void k_transq(const float* __restrict__ Whq, u16* __restrict__ WqT) {
  __shared__ float ti[64][65];
  int n0 = blockIdx.x * 64, k0 = blockIdx.y * 64;
  int c = threadIdx.x & 63, rq = threadIdx.x >> 6;
#pragma unroll
  for (int p = 0; p < 16; ++p) {
    int rr = p * 4 + rq;
    ti[rr][c] = Whq[(size_t)(k0 + rr) * V_ + n0 + c];
  }
  __syncthreads();
#pragma unroll
  for (int p = 0; p < 16; ++p) {
    int nn = p * 4 + rq;
    WqT[(size_t)(n0 + nn) * H_ + k0 + c] = f2bf(ti[c][nn]);
  }
}

// ---------------- fused kernel ----------------
__global__ __launch_bounds__(512)
void fused(const u16* __restrict__ WhT, const u16* __restrict__ WxT,
           const u16* __restrict__ WqT, const u16* __restrict__ Emb,
           float* __restrict__ Gx, u16* __restrict__ Hs,
           u32* __restrict__ ctl, const float* __restrict__ bfu,
           const float* __restrict__ bqv, float* __restrict__ out,
           float* __restrict__ outH, float* __restrict__ outC) {
  __shared__ __align__(16) char ldsbuf[132096];
  __shared__ u32 s_tk;
  const int bid = blockIdx.x;
  const int tid = threadIdx.x, l = tid & 63, w = tid >> 6;

  if (bid < NWORK) {
    // =============== WORKER: persistent recurrence ===============
    u16* Hlds = (u16*)ldsbuf;                              // 32 KB H[t] stage
    float (*gx)[16][16] = (float (*)[16][16])(ldsbuf + 32768);  // 8 KB
    const int wid = bid;
    const int gw = wid * 8 + w;                   // 0..255
    const int hu0 = gw * 4;
    const int c = l & 15;
    const int n = (c >> 2) * H_ + hu0 + (c & 3);
    const int koff = (l >> 4) * 8;
    const int kgrp = (l >> 4) * 2;
    const int m = l & 15, u = l >> 4;
    const int hu = hu0 + u;
    const int m4 = m * 4;

    bf16x8 wf[32];
    {
      const u16* bp = WhT + (size_t)n * H_ + koff;
#pragma unroll
      for (int kk = 0; kk < 32; ++kk) wf[kk] = ldb8(bp + kk * 32);
    }

    float Cs = 0.0f;
    u64* HsU64 = (u64*)Hs;
    const u32* myflag = &ctl[FL + (l & 31) * FLAG_STRIDE];

    for (int t = 0; t < T_; ++t) {
      // gate on Gx row-block availability (consumers produce t-ascending)
      if (tid == 0 && (t & 7) == 0) {
        while (ld_agent(&ctl[GXR + (t >> 3) * FLAG_STRIDE]) < 32u)
          __builtin_amdgcn_s_sleep(1);
      }
      if (t > 0 && w == 0) {
        while (true) {
          u32 v = ld_agent(myflag);
          if (__all((int)(v >= (u32)t))) break;
          __builtin_amdgcn_s_sleep(1);
        }
        if (gw == 0 && l == 0) st_agent(&ctl[PROG], (u32)t);
      }
      __syncthreads();                 // Gx + H[t] globally visible

      // stage H[t] (32 KB) into LDS: 4 x (512 thr x 16 B), linear
      {
        const u16* src = Hs + (size_t)t * 16384 + (size_t)w * 512 + (size_t)l * 8;
        char* dstb = (char*)Hlds + (size_t)w * 1024;
        gll16(src,         dstb);
        gll16(src + 4096,  dstb + 8192);
        gll16(src + 8192,  dstb + 16384);
        gll16(src + 12288, dstb + 24576);
      }
      const f32x4 g4 = *(const f32x4*)&Gx[((size_t)t * 4096 + n) * 16 + (size_t)(l >> 4) * 4];
      asm volatile("s_waitcnt vmcnt(0)" ::: "memory");
      __syncthreads();                 // Hlds ready

      const u16* hl = Hlds + m4;
      f32x4 a0 = {}, a1 = {}, a2 = {}, a3 = {};
#pragma unroll
      for (int kk = 0; kk < 32; kk += 4) {
        a0 = __builtin_amdgcn_mfma_f32_16x16x32_bf16(mk2(hl + (kgrp + (kk + 0) * 8) * 64), wf[kk + 0], a0, 0, 0, 0);
        a1 = __builtin_amdgcn_mfma_f32_16x16x32_bf16(mk2(hl + (kgrp + (kk + 1) * 8) * 64), wf[kk + 1], a1, 0, 0, 0);
        a2 = __builtin_amdgcn_mfma_f32_16x16x32_bf16(mk2(hl + (kgrp + (kk + 2) * 8) * 64), wf[kk + 2], a2, 0, 0, 0);
        a3 = __builtin_amdgcn_mfma_f32_16x16x32_bf16(mk2(hl + (kgrp + (kk + 3) * 8) * 64), wf[kk + 3], a3, 0, 0, 0);
      }
      f32x4 acc = (a0 + a1) + (a2 + a3);

#pragma unroll
      for (int j = 0; j < 4; ++j)
        gx[w][(l >> 4) * 4 + j][c] = acc[j] + g4[j];

      float gi = gx[w][m][0 + u];
      float gf = gx[w][m][4 + u];
      float go = gx[w][m][8 + u];
      float gc = gx[w][m][12 + u];
      float I = fsig(gi);
      float F = fsig(gf);
      float O = fsig(go);
      float Ct = ftanh(gc);
      Cs = F * Cs + I * Ct;
      float Hn = O * ftanh(Cs);

      u32 hb = (u32)f2bf(Hn);
      u32 h1 = __shfl_down(hb, 16);
      u32 h2 = __shfl_down(hb, 32);
      u32 h3 = __shfl_down(hb, 48);
      if (l < 16) {
        u64 pk = (u64)hb | ((u64)h1 << 16) | ((u64)h2 << 32) | ((u64)h3 << 48);
        st_agent64(&HsU64[(size_t)(t + 1) * 4096 + (size_t)gw * 16 + l], pk);
      }
      if (t == T_ - 1) {
        outH[(size_t)m * H_ + hu] = Hn;
        outC[(size_t)m * H_ + hu] = Cs;
      }

      // UNCONDITIONAL: own stores acked at MALL, block-wide, then flag store
      asm volatile("s_waitcnt vmcnt(0)" ::: "memory");
      __syncthreads();
      if (tid == 0) st_agent(&ctl[FL + wid * FLAG_STRIDE], (u32)(t + 1));
    }

    // publish final progress (Hs[256] visible once all flags reach 256)
    if (gw == 0) {
      while (true) {
        u32 v = ld_agent(myflag);
        if (__all((int)(v >= (u32)T_))) break;
        __builtin_amdgcn_s_sleep(1);
      }
      if (l == 0) st_agent(&ctl[PROG], (u32)T_);
    }
    return;
  }

  // =============== CONSUMER ===============
  const int cid = bid - NWORK;

  // ---- Phase 1: Gx tiles (ticket queue, t-ascending) ----
  {
    u16* As = (u16*)ldsbuf;          // [128][32] 8KB
    u16* Bs = As + 4096;             // [128][32] 8KB
    const int wm = (w & 1) * 64, wn = (w >> 1) * 32;
    const int koff = (l >> 4) * 8;
    const int srow = tid >> 2;
    const int scol = (tid & 3) * 8;
    u16* dstA = As + (size_t)w * 512;
    u16* dstB = Bs + (size_t)w * 512;

    for (;;) {
      __syncthreads();
      if (tid == 0)
        s_tk = __hip_atomic_fetch_add(&ctl[WQ], 1u, __ATOMIC_RELAXED, __HIP_MEMORY_SCOPE_AGENT);
      __syncthreads();
      u32 tk = s_tk;
      if (tk >= 1024u) break;
      const int mt = (int)(tk >> 5), nt = (int)(tk & 31);
      const int m0 = mt * 128, n0 = nt * 128;
      const u16* srcA = Emb + (size_t)(m0 + srow) * H_ + scol;
      const u16* srcB = WxT + (size_t)(n0 + srow) * H_ + scol;

      f32x4 acc[4][2] = {};
      for (int k0 = 0; k0 < H_; k0 += 32) {
        gll16(srcA + k0, dstA);
        gll16(srcB + k0, dstB);
        asm volatile("s_waitcnt vmcnt(0)" ::: "memory");
        __syncthreads();
        bf16x8 af[4], bfr[2];
#pragma unroll
        for (int tm = 0; tm < 4; ++tm)
          af[tm] = ldb8(&As[(wm + tm * 16 + (l & 15)) * 32 + koff]);
#pragma unroll
        for (int tn = 0; tn < 2; ++tn)
          bfr[tn] = ldb8(&Bs[(wn + tn * 16 + (l & 15)) * 32 + koff]);
#pragma unroll
        for (int tm = 0; tm < 4; ++tm)
#pragma unroll
          for (int tn = 0; tn < 2; ++tn)
            acc[tm][tn] = __builtin_amdgcn_mfma_f32_16x16x32_bf16(af[tm], bfr[tn], acc[tm][tn], 0, 0, 0);
        __syncthreads();
      }

#pragma unroll
      for (int tm = 0; tm < 4; ++tm) {
        int rbase = m0 + wm + tm * 16 + (l >> 4) * 4;
        int t = rbase >> 4;
        int bb = rbase & 15;
#pragma unroll
        for (int tn = 0; tn < 2; ++tn) {
          int nn = n0 + wn + tn * 16 + (l & 15);
          float bv = bfu[nn];
          union { float f[2]; u64 u; } p0, p1;
          p0.f[0] = acc[tm][tn][0] + bv; p0.f[1] = acc[tm][tn][1] + bv;
          p1.f[0] = acc[tm][tn][2] + bv; p1.f[1] = acc[tm][tn][3] + bv;
          u64* o = (u64*)&Gx[((size_t)t * 4096 + nn) * 16 + bb];
          st_agent64(&o[0], p0.u);
          st_agent64(&o[1], p1.u);
        }
      }
      asm volatile("s_waitcnt vmcnt(0)" ::: "memory");
      __syncthreads();
      if (tid == 0)
        __hip_atomic_fetch_add(&ctl[GXR + mt * FLAG_STRIDE], 1u, __ATOMIC_RELAXED, __HIP_MEMORY_SCOPE_AGENT);
    }
  }
  __syncthreads();

  // ---- Phase 2: Ys, mt-outer / strip-inner (r10-proven pacing) ----
  {
    u16* Bs = (u16*)ldsbuf;                     // [64][BSROW]
    const int nloc = (w & 3) * 16 + (l & 15);
    const int mhalf = w >> 2;
    const int koff = (l >> 4) * 8;
    const int kgrp = (l >> 4) * 2;
    const int m4 = (l & 15) * 4;
    const size_t tv = (size_t)T_ * V_;

    for (int mt = 0; mt < 32; ++mt) {
      if (tid == 0) {
        const u32 need = (u32)(mt * 8 + 8);
        while (ld_agent(&ctl[PROG]) < need)
          __builtin_amdgcn_s_sleep(16);
      }
      __syncthreads();

      for (int s = cid; s < NSTRIP; s += NCONS) {
        const int n0 = s * 64;
#pragma unroll
        for (int r8 = 0; r8 < 8; ++r8) {
          int row = w * 8 + r8;
          const u16* src = WqT + (size_t)(n0 + row) * H_;
          u16* dst = Bs + row * BSROW;
          gll16(src + l * 8, dst);
          gll16(src + 512 + l * 8, dst + 512);
        }
        asm volatile("s_waitcnt vmcnt(0)" ::: "memory");
        __syncthreads();

        f32x4 acc[4] = {};
        const u16* hbase = Hs + (size_t)(mt * 8 + mhalf * 4 + 1) * 16384 + m4;
        const u16* bsrow = Bs + nloc * BSROW + koff;
#pragma unroll 4
        for (int kk = 0; kk < 32; ++kk) {
          bf16x8 bf = ldb8(bsrow + kk * 32);
          const int qo = (kgrp + kk * 8) * 64;
          acc[0] = __builtin_amdgcn_mfma_f32_16x16x32_bf16(mk2(hbase + 0 * 16384 + qo), bf, acc[0], 0, 0, 0);
          acc[1] = __builtin_amdgcn_mfma_f32_16x16x32_bf16(mk2(hbase + 1 * 16384 + qo), bf, acc[1], 0, 0, 0);
          acc[2] = __builtin_amdgcn_mfma_f32_16x16x32_bf16(mk2(hbase + 2 * 16384 + qo), bf, acc[2], 0, 0, 0);
          acc[3] = __builtin_amdgcn_mfma_f32_16x16x32_bf16(mk2(hbase + 3 * 16384 + qo), bf, acc[3], 0, 0, 0);
        }

        const int nn = n0 + nloc;
        const float bv = bqv[nn];
#pragma unroll
        for (int tm = 0; tm < 4; ++tm) {
          const int t_glob = mt * 8 + mhalf * 4 + tm;
#pragma unroll
          for (int j = 0; j < 4; ++j) {
            out[(size_t)((l >> 4) * 4 + j) * tv + (size_t)t_glob * V_ + nn] = acc[tm][j] + bv;
          }
        }
        __syncthreads();   // Bs reads done before next strip's staging
      }
    }
  }
}

// ---------------- host launcher ----------------

extern "C" void kernel_launch(void* const* d_in, const int* in_sizes, int n_in,
                              void* d_out, int out_size, void* d_ws, size_t ws_size,
                              hipStream_t stream) {
  const int*   ids = (const int*)d_in[0];
  const float* emb = (const float*)d_in[1];
  const float* Wxi = (const float*)d_in[2];
  const float* Whi = (const float*)d_in[3];
  const float* bi  = (const float*)d_in[4];
  const float* Wxf = (const float*)d_in[5];
  const float* Whf = (const float*)d_in[6];
  const float* bfv = (const float*)d_in[7];
  const float* Wxo = (const float*)d_in[8];
  const float* Who = (const float*)d_in[9];
  const float* bo  = (const float*)d_in[10];
  const float* Wxc = (const float*)d_in[11];
  const float* Whc = (const float*)d_in[12];
  const float* bc  = (const float*)d_in[13];
  const float* Whq = (const float*)d_in[14];
  const float* bq  = (const float*)d_in[15];
  float* out = (float*)d_out;

  char* ws = (char*)d_ws;
  u16* WxT = (u16*)ws;      ws += (size_t)4096 * H_ * 2;
  u16* WhT = (u16*)ws;      ws += (size_t)4096 * H_ * 2;
  u16* WqT = (u16*)ws;      ws += (size_t)V_ * H_ * 2;
  u16* Emb = (u16*)ws;      ws += (size_t)T_ * B_ * H_ * 2;
  float* Gx = (float*)ws;   ws += (size_t)T_ * 4096 * B_ * 4;
  u16* Hs  = (u16*)ws;      ws += (size_t)(T_ + 1) * B_ * H_ * 2;
  float* bfu = (float*)ws;  ws += (size_t)4096 * 4;
  u32* ctl = (u32*)ws;      ws += (size_t)CTL_WORDS * 4;

  // prep
  k_init<<<64, 256, 0, stream>>>((u32*)Hs, ctl, bfu, bi, bfv, bo, bc);
  k_embed<<<4096, 256, 0, stream>>>(ids, emb, Emb);
  k_fuse8<<<dim3(16, 16, 8), 256, 0, stream>>>(Wxi, Wxf, Wxo, Wxc, Whi, Whf, Who, Whc, WxT, WhT);
  k_transq<<<dim3(500, 16), 256, 0, stream>>>(Whq, WqT);

  // fused: Gx producers + recurrence + Ys consumers
  float* outH = out + (size_t)B_ * T_ * V_;
  float* outC = outH + (size_t)B_ * H_;
  fused<<<NWORK + NCONS, 512, 0, stream>>>(WhT, WxT, WqT, Emb, Gx, Hs, ctl, bfu, bq,
                                           out, outH, outC);
}